// Round 3
// baseline (1076.367 us; speedup 1.0000x reference)
//
#include <hip/hip_runtime.h>
#include <hip/hip_bf16.h>

// ---- problem constants (match reference) ----
#define NYI 200
#define NXI 200
#define PMLW 20
#define FDP 2
#define PADW (PMLW + FDP)          // 22
#define NYP (NYI + 2 * PADW)       // 244
#define NXP (NXI + 2 * PADW)       // 244
#define NP  (NYP * NXP)            // 59536
#define NSH 2
#define NRECV 100
#define NTT 120
#define TOTC (NSH * NP)            // 119072

#define DTC   0.0005f
#define RH    0.25f                // 1/DY = 1/DX
#define RH2   0.0625f              // 1/DY^2
#define C1A   (1.0f / 12.0f)
#define C1B   (2.0f / 3.0f)
#define C2A   (1.0f / 12.0f)
#define C2B   (4.0f / 3.0f)

#define CELL_BLOCKS ((TOTC + 255) / 256)   // 466

// ---- workspace layout (float offsets) ----
#define OFF_MAXV 0
#define OFF_AY   64
#define OFF_BY   (OFF_AY + NYP)
#define OFF_AX   (OFF_BY + NYP)
#define OFF_BX   (OFF_AX + NXP)
#define OFF_V2   (OFF_BX + NXP)
#define OFF_SPV  (OFF_V2 + NP)
#define OFF_F    (OFF_SPV + NP)      // 12 * TOTC floats of fields

__device__ __forceinline__ float cellv(const float* p, int base, int y, int x) {
    if ((unsigned)y >= (unsigned)NYP || (unsigned)x >= (unsigned)NXP) return 0.0f;
    return p[base + y * NXP + x];
}

__global__ void reduce_max_kernel(const float* __restrict__ v, float* __restrict__ out) {
    __shared__ float sm[256];
    float m = 0.0f;
    for (int i = threadIdx.x; i < NYI * NXI; i += 256)
        m = fmaxf(m, v[i]);
    sm[threadIdx.x] = m;
    __syncthreads();
    for (int s = 128; s > 0; s >>= 1) {
        if (threadIdx.x < s) sm[threadIdx.x] = fmaxf(sm[threadIdx.x], sm[threadIdx.x + s]);
        __syncthreads();
    }
    if (threadIdx.x == 0) out[0] = sm[0];
}

__global__ void setup_kernel(const float* __restrict__ v,
                             const float* __restrict__ scat,
                             const float* __restrict__ maxv,
                             float* __restrict__ ay, float* __restrict__ by,
                             float* __restrict__ ax, float* __restrict__ bx,
                             float* __restrict__ v2dt2, float* __restrict__ spv) {
    int gtid = blockIdx.x * blockDim.x + threadIdx.x;
    int nth  = gridDim.x * blockDim.x;

    for (int idx = gtid; idx < NP; idx += nth) {
        int y = idx / NXP;
        int x = idx - y * NXP;
        int yi = min(max(y - PADW, 0), NYI - 1);
        int xi = min(max(x - PADW, 0), NXI - 1);
        float vp = v[yi * NXI + xi];
        v2dt2[idx] = vp * vp * DTC * DTC;
        float sp = 0.0f;
        int ys = y - PADW, xs = x - PADW;
        if (ys >= 0 && ys < NYI && xs >= 0 && xs < NXI)
            sp = scat[ys * NXI + xs];
        spv[idx] = 2.0f * vp * DTC * DTC * sp;
    }

    if (gtid < NYP + NXP) {
        float mv = maxv[0];
        int isY = gtid < NYP;
        int j   = isY ? gtid : gtid - NYP;
        int n   = isY ? NYP : NXP;
        float h = 4.0f;
        float xf = (float)j;
        float lo = (float)(FDP + PMLW);
        float hi = (float)(n - 1 - FDP - PMLW);
        float d1 = fminf(fmaxf((lo - xf) / (float)PMLW, 0.0f), 1.0f);
        float d2 = fminf(fmaxf((xf - hi) / (float)PMLW, 0.0f), 1.0f);
        float d  = fmaxf(d1, d2);
        float sigma = 3.0f * mv * 6.9077552790f / (2.0f * (float)PMLW * h) * d * d;
        float alpha = 6.2831853072f * 25.0f * (1.0f - d);
        float a  = expf(-(sigma + alpha) * DTC);
        float bb = sigma / (sigma + alpha + 1e-9f) * (a - 1.0f);
        if (isY) { ay[j] = a; by[j] = bb; }
        else     { ax[j] = a; bx[j] = bb; }
    }
}

// Phase A: psi updates (d1 of wavefields). Also records receivers for time t-1
// (wfcsc at entry == wfnsc of previous step, complete by launch ordering).
__global__ void phaseA_kernel(int t,
    const float* __restrict__ wfc, const float* __restrict__ wfcsc,
    float* __restrict__ psiy, float* __restrict__ psix,
    float* __restrict__ psiysc, float* __restrict__ psixsc,
    const float* __restrict__ ay, const float* __restrict__ by,
    const float* __restrict__ ax, const float* __restrict__ bx,
    const int* __restrict__ rloc, float* __restrict__ out)
{
    int idx = blockIdx.x * blockDim.x + threadIdx.x;

    if (idx < NSH * NRECV && t > 0) {
        int b = idx / NRECV;
        int ry = rloc[idx * 2 + 0] + PADW;
        int rx = rloc[idx * 2 + 1] + PADW;
        out[idx * NTT + (t - 1)] = wfcsc[b * NP + ry * NXP + rx];
    }

    if (idx >= TOTC) return;
    int b = (idx >= NP) ? 1 : 0;
    int cell = idx - b * NP;
    int y = cell / NXP;
    int x = cell - y * NXP;
    int base = b * NP;
    float ayv = ay[y], byv = by[y], axv = ax[x], bxv = bx[x];

    float d1yw = RH * (C1A * (cellv(wfc, base, y - 2, x) - cellv(wfc, base, y + 2, x)) +
                       C1B * (cellv(wfc, base, y + 1, x) - cellv(wfc, base, y - 1, x)));
    float d1xw = RH * (C1A * (cellv(wfc, base, y, x - 2) - cellv(wfc, base, y, x + 2)) +
                       C1B * (cellv(wfc, base, y, x + 1) - cellv(wfc, base, y, x - 1)));
    psiy[idx] = ayv * psiy[idx] + byv * d1yw;
    psix[idx] = axv * psix[idx] + bxv * d1xw;

    float d1ys = RH * (C1A * (cellv(wfcsc, base, y - 2, x) - cellv(wfcsc, base, y + 2, x)) +
                       C1B * (cellv(wfcsc, base, y + 1, x) - cellv(wfcsc, base, y - 1, x)));
    float d1xs = RH * (C1A * (cellv(wfcsc, base, y, x - 2) - cellv(wfcsc, base, y, x + 2)) +
                       C1B * (cellv(wfcsc, base, y, x + 1) - cellv(wfcsc, base, y, x - 1)));
    psiysc[idx] = ayv * psiysc[idx] + byv * d1ys;
    psixsc[idx] = axv * psixsc[idx] + bxv * d1xs;
}

// Phase B: zeta + wavefield time update. Writes new fields into wfp/wfpsc
// (overwriting the previous-step fields). Host swaps pointers afterwards.
__global__ void phaseB_kernel(int t,
    const float* __restrict__ wfc, float* __restrict__ wfp,
    const float* __restrict__ wfcsc, float* __restrict__ wfpsc,
    const float* __restrict__ psiy, const float* __restrict__ psix,
    float* __restrict__ zety, float* __restrict__ zetx,
    const float* __restrict__ psiysc, const float* __restrict__ psixsc,
    float* __restrict__ zetysc, float* __restrict__ zetxsc,
    const float* __restrict__ v2dt2, const float* __restrict__ spv,
    const float* __restrict__ ay, const float* __restrict__ by,
    const float* __restrict__ ax, const float* __restrict__ bx,
    const float* __restrict__ amps, const int* __restrict__ sloc)
{
    int idx = blockIdx.x * blockDim.x + threadIdx.x;
    if (idx >= TOTC) return;
    int b = (idx >= NP) ? 1 : 0;
    int cell = idx - b * NP;
    int y = cell / NXP;
    int x = cell - y * NXP;
    int base = b * NP;
    float ayv = ay[y], byv = by[y], axv = ax[x], bxv = bx[x];

    // background field
    float w0 = wfc[idx];
    float d2yw = RH2 * (C2B * (cellv(wfc, base, y - 1, x) + cellv(wfc, base, y + 1, x)) -
                        C2A * (cellv(wfc, base, y - 2, x) + cellv(wfc, base, y + 2, x)) -
                        2.5f * w0);
    float d2xw = RH2 * (C2B * (cellv(wfc, base, y, x - 1) + cellv(wfc, base, y, x + 1)) -
                        C2A * (cellv(wfc, base, y, x - 2) + cellv(wfc, base, y, x + 2)) -
                        2.5f * w0);
    float d1yp = RH * (C1A * (cellv(psiy, base, y - 2, x) - cellv(psiy, base, y + 2, x)) +
                       C1B * (cellv(psiy, base, y + 1, x) - cellv(psiy, base, y - 1, x)));
    float d1xp = RH * (C1A * (cellv(psix, base, y, x - 2) - cellv(psix, base, y, x + 2)) +
                       C1B * (cellv(psix, base, y, x + 1) - cellv(psix, base, y, x - 1)));
    float ty = d2yw + d1yp;
    float tx = d2xw + d1xp;
    float zy = ayv * zety[idx] + byv * ty;
    float zx = axv * zetx[idx] + bxv * tx;
    zety[idx] = zy;
    zetx[idx] = zx;
    float lap = ty + zy + tx + zx;

    // scattered field
    float ws0 = wfcsc[idx];
    float d2ys = RH2 * (C2B * (cellv(wfcsc, base, y - 1, x) + cellv(wfcsc, base, y + 1, x)) -
                        C2A * (cellv(wfcsc, base, y - 2, x) + cellv(wfcsc, base, y + 2, x)) -
                        2.5f * ws0);
    float d2xs = RH2 * (C2B * (cellv(wfcsc, base, y, x - 1) + cellv(wfcsc, base, y, x + 1)) -
                        C2A * (cellv(wfcsc, base, y, x - 2) + cellv(wfcsc, base, y, x + 2)) -
                        2.5f * ws0);
    float d1yps = RH * (C1A * (cellv(psiysc, base, y - 2, x) - cellv(psiysc, base, y + 2, x)) +
                        C1B * (cellv(psiysc, base, y + 1, x) - cellv(psiysc, base, y - 1, x)));
    float d1xps = RH * (C1A * (cellv(psixsc, base, y, x - 2) - cellv(psixsc, base, y, x + 2)) +
                        C1B * (cellv(psixsc, base, y, x + 1) - cellv(psixsc, base, y, x - 1)));
    float tys = d2ys + d1yps;
    float txs = d2xs + d1xps;
    float zys = ayv * zetysc[idx] + byv * tys;
    float zxs = axv * zetxsc[idx] + bxv * txs;
    zetysc[idx] = zys;
    zetxsc[idx] = zxs;
    float lapsc = tys + zys + txs + zxs;

    float v2 = v2dt2[cell];
    float wn   = v2 * lap   + 2.0f * w0  - wfp[idx];
    float wnsc = v2 * lapsc + 2.0f * ws0 - wfpsc[idx] + spv[cell] * lap;

    // source injection (one source per shot)
    int sy0 = sloc[0] + PADW, sx0 = sloc[1] + PADW;
    int sy1 = sloc[2] + PADW, sx1 = sloc[3] + PADW;
    if (b == 0 && y == sy0 && x == sx0) wn += v2 * amps[t];
    if (b == 1 && y == sy1 && x == sx1) wn += v2 * amps[NTT + t];

    wfp[idx]   = wn;
    wfpsc[idx] = wnsc;
}

__global__ void record_kernel(const float* __restrict__ wfcsc,
                              const int* __restrict__ rloc,
                              float* __restrict__ out) {
    int idx = threadIdx.x;
    if (idx < NSH * NRECV) {
        int b = idx / NRECV;
        int ry = rloc[idx * 2 + 0] + PADW;
        int rx = rloc[idx * 2 + 1] + PADW;
        out[idx * NTT + (NTT - 1)] = wfcsc[b * NP + ry * NXP + rx];
    }
}

extern "C" void kernel_launch(void* const* d_in, const int* in_sizes, int n_in,
                              void* d_out, int out_size, void* d_ws, size_t ws_size,
                              hipStream_t stream) {
    const float* v    = (const float*)d_in[0];
    const float* scat = (const float*)d_in[1];
    const float* amps = (const float*)d_in[2];
    const int* sloc = (const int*)d_in[3];
    const int* rloc = (const int*)d_in[4];
    float* ws = (float*)d_ws;
    float* out = (float*)d_out;

    float* ay  = ws + OFF_AY;
    float* by  = ws + OFF_BY;
    float* ax  = ws + OFF_AX;
    float* bx  = ws + OFF_BX;
    float* v2  = ws + OFF_V2;
    float* spv = ws + OFF_SPV;
    float* F   = ws + OFF_F;

    float* wfc    = F + 0 * TOTC;
    float* wfp    = F + 1 * TOTC;
    float* psiy   = F + 2 * TOTC;
    float* psix   = F + 3 * TOTC;
    float* zety   = F + 4 * TOTC;
    float* zetx   = F + 5 * TOTC;
    float* wfcsc  = F + 6 * TOTC;
    float* wfpsc  = F + 7 * TOTC;
    float* psiysc = F + 8 * TOTC;
    float* psixsc = F + 9 * TOTC;
    float* zetysc = F + 10 * TOTC;
    float* zetxsc = F + 11 * TOTC;

    // zero the 12 field arrays (ws is poisoned 0xAA before every timed call)
    hipMemsetAsync(F, 0, sizeof(float) * 12 * TOTC, stream);

    reduce_max_kernel<<<1, 256, 0, stream>>>(v, ws + OFF_MAXV);
    setup_kernel<<<(NP + 255) / 256, 256, 0, stream>>>(
        v, scat, ws + OFF_MAXV, ay, by, ax, bx, v2, spv);

    for (int t = 0; t < NTT; ++t) {
        phaseA_kernel<<<CELL_BLOCKS, 256, 0, stream>>>(
            t, wfc, wfcsc, psiy, psix, psiysc, psixsc,
            ay, by, ax, bx, rloc, out);
        phaseB_kernel<<<CELL_BLOCKS, 256, 0, stream>>>(
            t, wfc, wfp, wfcsc, wfpsc,
            psiy, psix, zety, zetx,
            psiysc, psixsc, zetysc, zetxsc,
            v2, spv, ay, by, ax, bx, amps, sloc);
        float* tmp;
        tmp = wfc;   wfc = wfp;     wfp = tmp;
        tmp = wfcsc; wfcsc = wfpsc; wfpsc = tmp;
    }
    record_kernel<<<1, 256, 0, stream>>>(wfcsc, rloc, out);
}